// Round 10
// baseline (214.161 us; speedup 1.0000x reference)
//
#include <hip/hip_runtime.h>
#include <stdint.h>

#define NB   16
#define CD   256
#define HW   1024
#define NQ   16384
#define KCN  8192

typedef unsigned long long u64;
typedef unsigned short     u16;
using f32x4  = __attribute__((ext_vector_type(4))) float;
using bf16x8 = __attribute__((ext_vector_type(8))) __bf16;

// ---------------- workspace layout (~16.9 MB) ----------------
#define ZTB_OFF  0            // u16  [NQ][CD]    8 MB  (z transposed, bf16)
#define EMBB_OFF 8388608      // u16  [KCN][CD]   4 MB  (emb, bf16)
#define EH_OFF   12582912     // f32  [KCN]      32 KB  (||e||^2/2 + 1024)
#define CAND_OFF 12615680     // u64  [NQ][32]    4 MB  (8 splits x 2 halves x top-2)

static __device__ __forceinline__ void gl_lds16(const void* g, void* l) {
  __builtin_amdgcn_global_load_lds(
      (const __attribute__((address_space(1))) void*)g,
      (__attribute__((address_space(3))) void*)l, 16, 0, 0);
}

static __device__ __forceinline__ unsigned bf16r(float x) {  // RNE fp32->bf16 bits
  unsigned u = __float_as_uint(x);
  return (u + 0x7fffu + ((u >> 16) & 1u)) >> 16;
}

static __device__ __forceinline__ u64 umin64(u64 a, u64 b) { return a < b ? a : b; }
static __device__ __forceinline__ u64 umax64(u64 a, u64 b) { return a < b ? b : a; }

// ---------------- kernel 1: merged prep ----------------
__global__ __launch_bounds__(256) void k_prep(const float* __restrict__ z,
                                              const float* __restrict__ emb,
                                              u16* __restrict__ zTb,
                                              u16* __restrict__ embB,
                                              float* __restrict__ eH) {
  const int bx = (int)blockIdx.x;
  if (bx < 1024) {
    __shared__ float tile[64][65];
    const int b   = bx >> 6;
    const int hwT = (bx >> 2) & 15;
    const int cT  = bx & 3;
    const int tx  = threadIdx.x & 63;
    const int ty  = threadIdx.x >> 6;
    const float* src = z + (size_t)(b * CD + cT * 64) * HW + hwT * 64;
#pragma unroll
    for (int i = 0; i < 16; ++i) {
      const int c_l = ty + 4 * i;
      tile[c_l][tx] = src[(size_t)c_l * HW + tx];
    }
    __syncthreads();
    const size_t dbase = (size_t)(b * HW + hwT * 64) * CD + cT * 64;
#pragma unroll
    for (int i = 0; i < 16; ++i) {
      const int hw_l = ty + 4 * i;
      zTb[dbase + (size_t)hw_l * CD + tx] = (u16)bf16r(tile[tx][hw_l]);
    }
  } else {
    const int wave = (bx - 1024) * 4 + ((int)threadIdx.x >> 6);  // 0..1023
    const int lane = threadIdx.x & 63;
#pragma unroll
    for (int it = 0; it < 8; ++it) {
      const int row = wave * 8 + it;
      const float4 v = *(const float4*)(emb + (size_t)row * CD + lane * 4);
      uint2 pk;
      pk.x = bf16r(v.x) | (bf16r(v.y) << 16);
      pk.y = bf16r(v.z) | (bf16r(v.w) << 16);
      *(uint2*)(embB + (size_t)row * CD + lane * 4) = pk;
      float s = v.x * v.x + v.y * v.y + v.z * v.z + v.w * v.w;
#pragma unroll
      for (int off = 32; off; off >>= 1) s += __shfl_xor(s, off, 64);
      if (lane == 0) eH[row] = 0.5f * s + 1024.0f;
    }
  }
}

// ---------------- kernel 2: MFMA GEMM + fused top-2 argmin (A-register-resident) ----------
// grid = 128 q-tiles * 8 splits = 1024; block 256 = 4 waves; wave w: queries (w&1)*64..+64,
// codes (w>>1)*64..+64. NT=8 n-tiles/block; K=256 in 4 chunks of BK=64.
// NEW vs R7: A-fragments depend only on kc, not nt -> loaded straight from global zTb into
// registers (16B dwordx4 per frag, L2-hot 64KB block slice), 2-deep kc rotation prefetched
// one interval ahead. LDS holds only Bs (16KB), per-interval DMA halves (16KB), ds_read
// halves (8 b128 per interval). Epilogue / cand layout identical to R7 (measured-good).
#define NT  8

__global__ __launch_bounds__(256, 2) void k_argmin(const u16* __restrict__ zTb,
                                                   const u16* __restrict__ embB,
                                                   const float* __restrict__ eH,
                                                   u64* __restrict__ cand) {
  __shared__ __align__(16) u16 Bs[128 * 64];   // 16 KB
  const int tid  = threadIdx.x;
  const int w    = tid >> 6;
  const int lane = tid & 63;
  const int l15  = lane & 15, quad = lane >> 4, l7 = lane & 7;
  const int q0    = (int)(blockIdx.x >> 3) * 128;
  const int split = (int)(blockIdx.x & 7);
  const int wq0 = (w & 1) * 64, wn0 = (w >> 1) * 64, wh = w >> 1;

  // B staging map (global_load_lds: wave-uniform base + lane*16), XOR-swizzled
  const int srowB = w * 32 + (lane >> 3);          // + i*8
  const int scol8 = (l7 ^ (lane >> 3)) * 8;        // logical chunk * 8 elems
  const int ldsL  = w * 4096 + lane * 16;          // + i*1024
  // B frag-read swizzled byte offsets within a row (row&7 == l7)
  const int co0 = ((0 * 4 + quad) ^ l7) * 16;
  const int co1 = ((1 * 4 + quad) ^ l7) * 16;

  // A direct-load base: frag elems zTb[q0+wq0+i*16+l15][kc*64+ks*32+quad*8 .. +8]
  const u16* abase = zTb + (size_t)(q0 + wq0 + l15) * CD + quad * 8;

  const float FMAX = __uint_as_float(0x7F7FFFFFu);
  float b1[16], b2[16];
#pragma unroll
  for (int s = 0; s < 16; ++s) { b1[s] = FMAX; b2[s] = FMAX; }

  f32x4 acc[4][4];

  bf16x8 aA[8], aB[8];
#pragma unroll
  for (int i = 0; i < 4; ++i)
#pragma unroll
    for (int ks = 0; ks < 2; ++ks)
      aA[i * 2 + ks] = *(const bf16x8*)(abase + (size_t)i * 16 * CD + ks * 32);

// one K-interval: stage B(kc), prefetch A[kcn] into NXT regs, barrier, MFMA with CUR, barrier
#define KSTEP(CUR, NXT, KC, KCN)                                                   \
  do {                                                                             \
    _Pragma("unroll")                                                              \
    for (int i = 0; i < 4; ++i)                                                    \
      gl_lds16(embB + (size_t)(n0 + srowB + i * 8) * CD + (KC) * 64 + scol8,       \
               (char*)Bs + ldsL + i * 1024);                                       \
    _Pragma("unroll")                                                              \
    for (int i = 0; i < 4; ++i)                                                    \
      _Pragma("unroll")                                                            \
      for (int ks = 0; ks < 2; ++ks)                                               \
        NXT[i * 2 + ks] =                                                          \
            *(const bf16x8*)(abase + (size_t)i * 16 * CD + (KCN) * 64 + ks * 32);  \
    __syncthreads();                                                               \
    _Pragma("unroll")                                                              \
    for (int ks = 0; ks < 2; ++ks) {                                               \
      const int co = ks ? co1 : co0;                                               \
      bf16x8 bfr[4];                                                               \
      _Pragma("unroll")                                                            \
      for (int j = 0; j < 4; ++j)                                                  \
        bfr[j] = *(const bf16x8*)((const char*)Bs + (wn0 + j * 16 + l15) * 128 + co); \
      _Pragma("unroll")                                                            \
      for (int i = 0; i < 4; ++i)                                                  \
        _Pragma("unroll")                                                          \
        for (int j = 0; j < 4; ++j)                                                \
          acc[i][j] = __builtin_amdgcn_mfma_f32_16x16x32_bf16(CUR[i * 2 + ks],     \
                                                              bfr[j], acc[i][j],   \
                                                              0, 0, 0);            \
    }                                                                              \
    __syncthreads();                                                               \
  } while (0)

  for (int nt = 0; nt < NT; ++nt) {
    const int n0 = split * 1024 + nt * 128;
    float eh[4];
#pragma unroll
    for (int j = 0; j < 4; ++j) eh[j] = eH[n0 + wn0 + 16 * j + l15];

#pragma unroll
    for (int i = 0; i < 4; ++i)
#pragma unroll
      for (int j = 0; j < 4; ++j) acc[i][j] = f32x4{0.f, 0.f, 0.f, 0.f};

    KSTEP(aA, aB, 0, 1);
    KSTEP(aB, aA, 1, 2);
    KSTEP(aA, aB, 2, 3);
    KSTEP(aB, aA, 3, 0);   // wraps: preloads A[0] for next nt

    // ---- fp32 epilogue: key = (||e||^2/2+1024) - z.e, quantized, id=(nt*4+j) in low 5 bits
#pragma unroll
    for (int i = 0; i < 4; ++i) {
#pragma unroll
      for (int r = 0; r < 4; ++r) {
        const int s = i * 4 + r;
        float kq[4];
#pragma unroll
        for (int j = 0; j < 4; ++j) {
          const unsigned kb = (__float_as_uint(eh[j] - acc[i][j][r]) & ~31u)
                              | (unsigned)(nt * 4 + j);
          kq[j] = __uint_as_float(kb);
        }
        const float lo01 = fminf(kq[0], kq[1]), hi01 = fmaxf(kq[0], kq[1]);
        const float lo23 = fminf(kq[2], kq[3]), hi23 = fmaxf(kq[2], kq[3]);
        const float best = fminf(lo01, lo23);
        const float sec  = fminf(fmaxf(lo01, lo23), fminf(hi01, hi23));
        b2[s] = fminf(fmaxf(best, b1[s]), fminf(sec, b2[s]));
        b1[s] = fminf(best, b1[s]);
      }
    }
  }
#undef KSTEP

  // ---- once per block: u64 butterfly top-2 merge (lane id in low bits), write cand
#pragma unroll
  for (int s = 0; s < 16; ++s) {
    u64 x1 = ((u64)__float_as_uint(b1[s]) << 32) | (unsigned)l15;
    u64 x2 = ((u64)__float_as_uint(b2[s]) << 32) | (unsigned)l15;
#pragma unroll
    for (int off = 1; off < 16; off <<= 1) {
      const u64 o1 = __shfl_xor(x1, off, 64);
      const u64 o2 = __shfl_xor(x2, off, 64);
      const u64 lo = umin64(x1, o1);
      const u64 hi = umax64(x1, o1);
      x1 = lo;
      x2 = umin64(hi, umin64(x2, o2));
    }
    if (l15 == 0) {
      const int i = s >> 2, r = s & 3;
      const int q = q0 + wq0 + i * 16 + quad * 4 + r;
      const unsigned kb1 = (unsigned)(x1 >> 32), kb2 = (unsigned)(x2 >> 32);
      const int n1 = split * 1024 + (int)((kb1 >> 2) & 7) * 128 + wn0
                     + 16 * (int)(kb1 & 3) + (int)(x1 & 15);
      const int n2 = split * 1024 + (int)((kb2 >> 2) & 7) * 128 + wn0
                     + 16 * (int)(kb2 & 3) + (int)(x2 & 15);
      cand[(size_t)q * 32 + split * 4 + wh * 2 + 0] = ((u64)kb1 << 32) | (unsigned)n1;
      cand[(size_t)q * 32 + split * 4 + wh * 2 + 1] = ((u64)kb2 << 32) | (unsigned)n2;
    }
  }
}

// ---------------- kernel 3: select + fp64 rescore (native z) + output ----------------
__global__ __launch_bounds__(256) void k_pick_out(const float* __restrict__ z,
                                                  const float* __restrict__ emb,
                                                  const u64* __restrict__ cand,
                                                  float* __restrict__ out) {
  __shared__ float zs[16][257];
  __shared__ float tile[16][257];
  const int t    = (int)threadIdx.x;
  const int lane = t & 63;
  const int wv   = t >> 6;
  const int sub  = lane >> 4;
  const int l15  = lane & 15;
  const int q0b  = (int)blockIdx.x * 16;
  const int b    = q0b >> 10, hw0 = q0b & 1023;
  const int q    = q0b + wv * 4 + sub;
  const int hwl  = wv * 4 + sub;

  // ---- phase 0: stage z slice (thread t = channel)
  {
    const float* zp = z + ((size_t)(b * CD + t)) * HW + hw0;
    const float4 a0 = *(const float4*)(zp + 0);
    const float4 a1 = *(const float4*)(zp + 4);
    const float4 a2 = *(const float4*)(zp + 8);
    const float4 a3 = *(const float4*)(zp + 12);
    zs[0][t] = a0.x;  zs[1][t] = a0.y;  zs[2][t] = a0.z;  zs[3][t] = a0.w;
    zs[4][t] = a1.x;  zs[5][t] = a1.y;  zs[6][t] = a1.z;  zs[7][t] = a1.w;
    zs[8][t] = a2.x;  zs[9][t] = a2.y;  zs[10][t] = a2.z; zs[11][t] = a2.w;
    zs[12][t] = a3.x; zs[13][t] = a3.y; zs[14][t] = a3.z; zs[15][t] = a3.w;
  }
  __syncthreads();

  // ---- phase 1: top-4-of-32 select (butterfly merge of sorted-2 lists)
  const u64* cp = cand + (size_t)q * 32 + l15 * 2;
  const u64 v0 = cp[0], v1 = cp[1];
  u64 s0 = umin64(v0, v1), s1 = umax64(v0, v1), s2 = ~0ull, s3 = ~0ull;
#pragma unroll
  for (int off = 1; off < 16; off <<= 1) {
    const u64 b0 = __shfl_xor(s0, off, 64);
    const u64 b1 = __shfl_xor(s1, off, 64);
    const u64 b2 = __shfl_xor(s2, off, 64);
    const u64 b3 = __shfl_xor(s3, off, 64);
    const u64 c0 = umin64(s0, b0);
    const u64 c1 = umin64(umin64(s1, b1), umax64(s0, b0));
    const u64 c2 = umin64(umin64(s2, b2),
                          umin64(umax64(s1, b0), umax64(s0, b1)));
    const u64 c3 = umin64(umin64(umin64(s3, b3), umax64(s2, b0)),
                          umin64(umax64(s0, b2), umax64(s1, b1)));
    s0 = c0; s1 = c1; s2 = c2; s3 = c3;
  }
  const u64 sel[4] = {s0, s1, s2, s3};

  // ---- phase 2: fp64 rescore, lane handles channels c = j*16 + l15
  float zq[16];
#pragma unroll
  for (int j = 0; j < 16; ++j) zq[j] = zs[hwl][j * 16 + l15];

  double bd = 1e300;
  int bi = 0x7fffffff;
  float keep[16];
#pragma unroll
  for (int j = 0; j < 16; ++j) keep[j] = 0.f;
#pragma unroll
  for (int c4 = 0; c4 < 4; ++c4) {
    const int idx = (int)(unsigned)(sel[c4] & 0xffffffffull);
    const float* er = emb + (size_t)idx * CD;
    float ev[16];
#pragma unroll
    for (int j = 0; j < 16; ++j) ev[j] = er[j * 16 + l15];
    double s = 0.0;
#pragma unroll
    for (int j = 0; j < 16; ++j) {
      const double d = (double)zq[j] - (double)ev[j];
      s += d * d;
    }
#pragma unroll
    for (int off = 1; off < 16; off <<= 1) s += __shfl_xor(s, off, 64);
    const bool better = (s < bd) || (s == bd && idx < bi);  // uniform in 16-lane group
    if (better) {
      bd = s; bi = idx;
#pragma unroll
      for (int j = 0; j < 16; ++j) keep[j] = ev[j];
    }
  }
  // ---- phase 3: winner row -> tile, transpose-store to out
#pragma unroll
  for (int j = 0; j < 16; ++j) tile[hwl][j * 16 + l15] = keep[j];
  __syncthreads();
  const int cluster = t >> 4;   // 0..15
  const int ll      = t & 15;
  float* obase = out + (size_t)b * CD * HW + hw0 + ll;
#pragma unroll
  for (int j = 0; j < 16; ++j) {
    const int c = 16 * j + cluster;
    obase[(size_t)c * HW] = tile[ll][c];
  }
}

extern "C" void kernel_launch(void* const* d_in, const int* in_sizes, int n_in,
                              void* d_out, int out_size, void* d_ws, size_t ws_size,
                              hipStream_t stream) {
  const float* z   = (const float*)d_in[0];
  const float* emb = (const float*)d_in[1];
  float* out = (float*)d_out;

  char* ws = (char*)d_ws;
  u16*   zTb  = (u16*)(ws + ZTB_OFF);
  u16*   embB = (u16*)(ws + EMBB_OFF);
  float* eH   = (float*)(ws + EH_OFF);
  u64*   cand = (u64*)(ws + CAND_OFF);

  k_prep<<<1280, 256, 0, stream>>>(z, emb, zTb, embB, eH);
  k_argmin<<<1024, 256, 0, stream>>>(zTb, embB, eH, cand);
  k_pick_out<<<1024, 256, 0, stream>>>(z, emb, cand, out);
}

// Round 11
// 177.861 us; speedup vs baseline: 1.2041x; 1.2041x over previous
//
#include <hip/hip_runtime.h>
#include <stdint.h>

#define NB   16
#define CD   256
#define HW   1024
#define NQ   16384
#define KCN  8192

typedef unsigned long long u64;
typedef unsigned short     u16;
using f32x4  = __attribute__((ext_vector_type(4))) float;
using bf16x8 = __attribute__((ext_vector_type(8))) __bf16;

// ---------------- workspace layout (~16.9 MB) ----------------
#define ZTB_OFF  0            // u16  [NQ][CD]    8 MB  (z transposed, bf16)
#define EMBB_OFF 8388608      // u16  [KCN][CD]   4 MB  (emb, bf16)
#define EH_OFF   12582912     // f32  [KCN]      32 KB  (||e||^2/2 + 1024)
#define CAND_OFF 12615680     // u64  [NQ][32]    4 MB  (8 splits x 2 halves x top-2)

static __device__ __forceinline__ void gl_lds16(const void* g, void* l) {
  __builtin_amdgcn_global_load_lds(
      (const __attribute__((address_space(1))) void*)g,
      (__attribute__((address_space(3))) void*)l, 16, 0, 0);
}

static __device__ __forceinline__ unsigned bf16r(float x) {  // RNE fp32->bf16 bits
  unsigned u = __float_as_uint(x);
  return (u + 0x7fffu + ((u >> 16) & 1u)) >> 16;
}

static __device__ __forceinline__ u64 umin64(u64 a, u64 b) { return a < b ? a : b; }
static __device__ __forceinline__ u64 umax64(u64 a, u64 b) { return a < b ? b : a; }

// ---------------- kernel 1: merged prep ----------------
__global__ __launch_bounds__(256) void k_prep(const float* __restrict__ z,
                                              const float* __restrict__ emb,
                                              u16* __restrict__ zTb,
                                              u16* __restrict__ embB,
                                              float* __restrict__ eH) {
  const int bx = (int)blockIdx.x;
  if (bx < 1024) {
    __shared__ float tile[64][65];
    const int b   = bx >> 6;
    const int hwT = (bx >> 2) & 15;
    const int cT  = bx & 3;
    const int tx  = threadIdx.x & 63;
    const int ty  = threadIdx.x >> 6;
    const float* src = z + (size_t)(b * CD + cT * 64) * HW + hwT * 64;
#pragma unroll
    for (int i = 0; i < 16; ++i) {
      const int c_l = ty + 4 * i;
      tile[c_l][tx] = src[(size_t)c_l * HW + tx];
    }
    __syncthreads();
    const size_t dbase = (size_t)(b * HW + hwT * 64) * CD + cT * 64;
#pragma unroll
    for (int i = 0; i < 16; ++i) {
      const int hw_l = ty + 4 * i;
      zTb[dbase + (size_t)hw_l * CD + tx] = (u16)bf16r(tile[tx][hw_l]);
    }
  } else {
    const int wave = (bx - 1024) * 4 + ((int)threadIdx.x >> 6);  // 0..1023
    const int lane = threadIdx.x & 63;
#pragma unroll
    for (int it = 0; it < 8; ++it) {
      const int row = wave * 8 + it;
      const float4 v = *(const float4*)(emb + (size_t)row * CD + lane * 4);
      uint2 pk;
      pk.x = bf16r(v.x) | (bf16r(v.y) << 16);
      pk.y = bf16r(v.z) | (bf16r(v.w) << 16);
      *(uint2*)(embB + (size_t)row * CD + lane * 4) = pk;
      float s = v.x * v.x + v.y * v.y + v.z * v.z + v.w * v.w;
#pragma unroll
      for (int off = 32; off; off >>= 1) s += __shfl_xor(s, off, 64);
      if (lane == 0) eH[row] = 0.5f * s + 1024.0f;
    }
  }
}

// ---------------- kernel 2: MFMA GEMM + fused top-2 argmin (R9 + LDS double-buffer) --------
// grid = 128 q-tiles * 8 splits = 1024; block 256 = 4 waves; wave w: queries (w&1)*64..+64,
// codes (w>>1)*64..+64. NT=8 n-tiles/block; K=256 in 4 chunks of BK=64.
// Double-buffered LDS (A0/B0, A1/B1, 64KB total): DMA for chunk kc+1 issued at the TOP of
// interval kc -> a full MFMA interval to complete before its barrier; ONE barrier/interval
// (33/block vs R9's 64). XOR swizzle unchanged (measured 0 conflicts). fp32-key epilogue.
#define NT  8

__global__ __launch_bounds__(256, 2) void k_argmin(const u16* __restrict__ zTb,
                                                   const u16* __restrict__ embB,
                                                   const float* __restrict__ eH,
                                                   u64* __restrict__ cand) {
  __shared__ __align__(16) u16 As0[128 * 64];   // 16 KB each
  __shared__ __align__(16) u16 Bs0[128 * 64];
  __shared__ __align__(16) u16 As1[128 * 64];
  __shared__ __align__(16) u16 Bs1[128 * 64];
  const int tid  = threadIdx.x;
  const int w    = tid >> 6;
  const int lane = tid & 63;
  const int l15  = lane & 15, quad = lane >> 4, l7 = lane & 7;
  const int q0    = (int)(blockIdx.x >> 3) * 128;
  const int split = (int)(blockIdx.x & 7);
  const int wq0 = (w & 1) * 64, wn0 = (w >> 1) * 64, wh = w >> 1;

  const int srow  = w * 32 + (lane >> 3);          // + i*8
  const int scol8 = (l7 ^ (lane >> 3)) * 8;        // logical chunk * 8 elems
  const int ldsL  = w * 4096 + lane * 16;          // byte offset, + i*1024
  const int co0 = ((0 * 4 + quad) ^ l7) * 16;      // frag-read swizzled offsets
  const int co1 = ((1 * 4 + quad) ^ l7) * 16;

  const float FMAX = __uint_as_float(0x7F7FFFFFu);
  float b1[16], b2[16];
#pragma unroll
  for (int s = 0; s < 16; ++s) { b1[s] = FMAX; b2[s] = FMAX; }

  f32x4 acc[4][4];

  // stage (A kc=0, B nt=0 kc=0) into buffer 0
  {
    const int n0i = split * 1024;
#pragma unroll
    for (int i = 0; i < 4; ++i) {
      const int row = srow + i * 8;
      gl_lds16(zTb  + (size_t)(q0 + row) * CD + 0 * 64 + scol8,
               (char*)As0 + ldsL + i * 1024);
      gl_lds16(embB + (size_t)(n0i + row) * CD + 0 * 64 + scol8,
               (char*)Bs0 + ldsL + i * 1024);
    }
  }
  __syncthreads();

// one K-interval: prefetch (NKC, NN0) into the idle buffer, MFMA from (PA,PB), barrier
#define KSTEP(PA, PB, NA, NBuf, NKC, NN0)                                            \
  do {                                                                               \
    _Pragma("unroll")                                                                \
    for (int i = 0; i < 4; ++i) {                                                    \
      const int row = srow + i * 8;                                                  \
      gl_lds16(zTb  + (size_t)(q0 + row) * CD + (NKC) * 64 + scol8,                  \
               (char*)NA + ldsL + i * 1024);                                         \
      gl_lds16(embB + (size_t)((NN0) + row) * CD + (NKC) * 64 + scol8,               \
               (char*)NBuf + ldsL + i * 1024);                                       \
    }                                                                                \
    _Pragma("unroll")                                                                \
    for (int ks = 0; ks < 2; ++ks) {                                                 \
      const int co = ks ? co1 : co0;                                                 \
      bf16x8 af[4], bfr[4];                                                          \
      _Pragma("unroll")                                                              \
      for (int i = 0; i < 4; ++i)                                                    \
        af[i] = *(const bf16x8*)((const char*)PA + (wq0 + i * 16 + l15) * 128 + co); \
      _Pragma("unroll")                                                              \
      for (int j = 0; j < 4; ++j)                                                    \
        bfr[j] = *(const bf16x8*)((const char*)PB + (wn0 + j * 16 + l15) * 128 + co);\
      _Pragma("unroll")                                                              \
      for (int i = 0; i < 4; ++i)                                                    \
        _Pragma("unroll")                                                            \
        for (int j = 0; j < 4; ++j)                                                  \
          acc[i][j] = __builtin_amdgcn_mfma_f32_16x16x32_bf16(af[i], bfr[j],         \
                                                              acc[i][j], 0, 0, 0);   \
    }                                                                                \
    __syncthreads();                                                                 \
  } while (0)

  for (int nt = 0; nt < NT; ++nt) {
    const int n0  = split * 1024 + nt * 128;
    const int n0n = (nt == NT - 1) ? n0 : n0 + 128;   // last: dummy in-bounds re-stage
    float eh[4];
#pragma unroll
    for (int j = 0; j < 4; ++j) eh[j] = eH[n0 + wn0 + 16 * j + l15];

#pragma unroll
    for (int i = 0; i < 4; ++i)
#pragma unroll
      for (int j = 0; j < 4; ++j) acc[i][j] = f32x4{0.f, 0.f, 0.f, 0.f};

    KSTEP(As0, Bs0, As1, Bs1, 1, n0);    // compute kc=0, prefetch kc=1
    KSTEP(As1, Bs1, As0, Bs0, 2, n0);    // compute kc=1, prefetch kc=2
    KSTEP(As0, Bs0, As1, Bs1, 3, n0);    // compute kc=2, prefetch kc=3
    KSTEP(As1, Bs1, As0, Bs0, 0, n0n);   // compute kc=3, prefetch next nt's kc=0

    // ---- fp32 epilogue: key = (||e||^2/2+1024) - z.e, quantized, id=(nt*4+j) in low 5 bits
#pragma unroll
    for (int i = 0; i < 4; ++i) {
#pragma unroll
      for (int r = 0; r < 4; ++r) {
        const int s = i * 4 + r;
        float kq[4];
#pragma unroll
        for (int j = 0; j < 4; ++j) {
          const unsigned kb = (__float_as_uint(eh[j] - acc[i][j][r]) & ~31u)
                              | (unsigned)(nt * 4 + j);
          kq[j] = __uint_as_float(kb);
        }
        const float lo01 = fminf(kq[0], kq[1]), hi01 = fmaxf(kq[0], kq[1]);
        const float lo23 = fminf(kq[2], kq[3]), hi23 = fmaxf(kq[2], kq[3]);
        const float best = fminf(lo01, lo23);
        const float sec  = fminf(fmaxf(lo01, lo23), fminf(hi01, hi23));
        b2[s] = fminf(fmaxf(best, b1[s]), fminf(sec, b2[s]));
        b1[s] = fminf(best, b1[s]);
      }
    }
  }
#undef KSTEP

  // ---- once per block: u64 butterfly top-2 merge (lane id in low bits), write cand
#pragma unroll
  for (int s = 0; s < 16; ++s) {
    u64 x1 = ((u64)__float_as_uint(b1[s]) << 32) | (unsigned)l15;
    u64 x2 = ((u64)__float_as_uint(b2[s]) << 32) | (unsigned)l15;
#pragma unroll
    for (int off = 1; off < 16; off <<= 1) {
      const u64 o1 = __shfl_xor(x1, off, 64);
      const u64 o2 = __shfl_xor(x2, off, 64);
      const u64 lo = umin64(x1, o1);
      const u64 hi = umax64(x1, o1);
      x1 = lo;
      x2 = umin64(hi, umin64(x2, o2));
    }
    if (l15 == 0) {
      const int i = s >> 2, r = s & 3;
      const int q = q0 + wq0 + i * 16 + quad * 4 + r;
      const unsigned kb1 = (unsigned)(x1 >> 32), kb2 = (unsigned)(x2 >> 32);
      const int n1 = split * 1024 + (int)((kb1 >> 2) & 7) * 128 + wn0
                     + 16 * (int)(kb1 & 3) + (int)(x1 & 15);
      const int n2 = split * 1024 + (int)((kb2 >> 2) & 7) * 128 + wn0
                     + 16 * (int)(kb2 & 3) + (int)(x2 & 15);
      cand[(size_t)q * 32 + split * 4 + wh * 2 + 0] = ((u64)kb1 << 32) | (unsigned)n1;
      cand[(size_t)q * 32 + split * 4 + wh * 2 + 1] = ((u64)kb2 << 32) | (unsigned)n2;
    }
  }
}

// ---------------- kernel 3: select + fp64 rescore (native z) + output ----------------
__global__ __launch_bounds__(256) void k_pick_out(const float* __restrict__ z,
                                                  const float* __restrict__ emb,
                                                  const u64* __restrict__ cand,
                                                  float* __restrict__ out) {
  __shared__ float zs[16][257];
  __shared__ float tile[16][257];
  const int t    = (int)threadIdx.x;
  const int lane = t & 63;
  const int wv   = t >> 6;
  const int sub  = lane >> 4;
  const int l15  = lane & 15;
  const int q0b  = (int)blockIdx.x * 16;
  const int b    = q0b >> 10, hw0 = q0b & 1023;
  const int q    = q0b + wv * 4 + sub;
  const int hwl  = wv * 4 + sub;

  // ---- phase 0: stage z slice (thread t = channel)
  {
    const float* zp = z + ((size_t)(b * CD + t)) * HW + hw0;
    const float4 a0 = *(const float4*)(zp + 0);
    const float4 a1 = *(const float4*)(zp + 4);
    const float4 a2 = *(const float4*)(zp + 8);
    const float4 a3 = *(const float4*)(zp + 12);
    zs[0][t] = a0.x;  zs[1][t] = a0.y;  zs[2][t] = a0.z;  zs[3][t] = a0.w;
    zs[4][t] = a1.x;  zs[5][t] = a1.y;  zs[6][t] = a1.z;  zs[7][t] = a1.w;
    zs[8][t] = a2.x;  zs[9][t] = a2.y;  zs[10][t] = a2.z; zs[11][t] = a2.w;
    zs[12][t] = a3.x; zs[13][t] = a3.y; zs[14][t] = a3.z; zs[15][t] = a3.w;
  }
  __syncthreads();

  // ---- phase 1: top-4-of-32 select (butterfly merge of sorted-2 lists)
  const u64* cp = cand + (size_t)q * 32 + l15 * 2;
  const u64 v0 = cp[0], v1 = cp[1];
  u64 s0 = umin64(v0, v1), s1 = umax64(v0, v1), s2 = ~0ull, s3 = ~0ull;
#pragma unroll
  for (int off = 1; off < 16; off <<= 1) {
    const u64 b0 = __shfl_xor(s0, off, 64);
    const u64 b1 = __shfl_xor(s1, off, 64);
    const u64 b2 = __shfl_xor(s2, off, 64);
    const u64 b3 = __shfl_xor(s3, off, 64);
    const u64 c0 = umin64(s0, b0);
    const u64 c1 = umin64(umin64(s1, b1), umax64(s0, b0));
    const u64 c2 = umin64(umin64(s2, b2),
                          umin64(umax64(s1, b0), umax64(s0, b1)));
    const u64 c3 = umin64(umin64(umin64(s3, b3), umax64(s2, b0)),
                          umin64(umax64(s0, b2), umax64(s1, b1)));
    s0 = c0; s1 = c1; s2 = c2; s3 = c3;
  }
  const u64 sel[4] = {s0, s1, s2, s3};

  // ---- phase 2: fp64 rescore, lane handles channels c = j*16 + l15
  float zq[16];
#pragma unroll
  for (int j = 0; j < 16; ++j) zq[j] = zs[hwl][j * 16 + l15];

  double bd = 1e300;
  int bi = 0x7fffffff;
  float keep[16];
#pragma unroll
  for (int j = 0; j < 16; ++j) keep[j] = 0.f;
#pragma unroll
  for (int c4 = 0; c4 < 4; ++c4) {
    const int idx = (int)(unsigned)(sel[c4] & 0xffffffffull);
    const float* er = emb + (size_t)idx * CD;
    float ev[16];
#pragma unroll
    for (int j = 0; j < 16; ++j) ev[j] = er[j * 16 + l15];
    double s = 0.0;
#pragma unroll
    for (int j = 0; j < 16; ++j) {
      const double d = (double)zq[j] - (double)ev[j];
      s += d * d;
    }
#pragma unroll
    for (int off = 1; off < 16; off <<= 1) s += __shfl_xor(s, off, 64);
    const bool better = (s < bd) || (s == bd && idx < bi);  // uniform in 16-lane group
    if (better) {
      bd = s; bi = idx;
#pragma unroll
      for (int j = 0; j < 16; ++j) keep[j] = ev[j];
    }
  }
  // ---- phase 3: winner row -> tile, transpose-store to out
#pragma unroll
  for (int j = 0; j < 16; ++j) tile[hwl][j * 16 + l15] = keep[j];
  __syncthreads();
  const int cluster = t >> 4;   // 0..15
  const int ll      = t & 15;
  float* obase = out + (size_t)b * CD * HW + hw0 + ll;
#pragma unroll
  for (int j = 0; j < 16; ++j) {
    const int c = 16 * j + cluster;
    obase[(size_t)c * HW] = tile[ll][c];
  }
}

extern "C" void kernel_launch(void* const* d_in, const int* in_sizes, int n_in,
                              void* d_out, int out_size, void* d_ws, size_t ws_size,
                              hipStream_t stream) {
  const float* z   = (const float*)d_in[0];
  const float* emb = (const float*)d_in[1];
  float* out = (float*)d_out;

  char* ws = (char*)d_ws;
  u16*   zTb  = (u16*)(ws + ZTB_OFF);
  u16*   embB = (u16*)(ws + EMBB_OFF);
  float* eH   = (float*)(ws + EH_OFF);
  u64*   cand = (u64*)(ws + CAND_OFF);

  k_prep<<<1280, 256, 0, stream>>>(z, emb, zTb, embB, eH);
  k_argmin<<<1024, 256, 0, stream>>>(zTb, embB, eH, cand);
  k_pick_out<<<1024, 256, 0, stream>>>(z, emb, cand, out);
}